// Round 4
// baseline (131.468 us; speedup 1.0000x reference)
//
#include <hip/hip_runtime.h>

#define CIN   128
#define HH    224
#define WW    224
#define COUT  256
#define HO    222
#define WO    222
#define PLANE (224 * 224 * 64)   // one channel-half plane of packed x, in elems

typedef unsigned short u16;
typedef unsigned int   u32;
typedef __bf16  bf16x8 __attribute__((ext_vector_type(8)));
typedef float   f32x4  __attribute__((ext_vector_type(4)));

__device__ __forceinline__ u16 f2bf(float f) {
  union { float f; u32 u; } v; v.f = f;
  u32 u = v.u;
  return (u16)((u + 0x7FFFu + ((u >> 16) & 1u)) >> 16);  // RNE
}

// ---------------- merged pre-pass ----------------
// x-pack blocks are XCD-aligned with the consumer: conv's band k (=bx&7 under
// round-robin dispatch) reads rows k*28..k*28+29, so pack row h on XCD h/28 —
// the packed row lands dirty in the L2 that will DMA it.
// xp: [ch(2)][h(224)][w(224)][jc'(8)][e(8)] bf16, block jc' holds c-block jc'^(w&7)
// wp: [mt(2)][kh(3)][ch(2)][kw(3)][mr(128)][jc'(8)][e(8)], jc' holds jc'^(mr&7)
__global__ void prep(const float* __restrict__ x, const float* __restrict__ w,
                     u16* __restrict__ xp, u16* __restrict__ wp) {
  const int t = threadIdx.x;
  if (blockIdx.x < 448) {
    const int xcd = blockIdx.x & 7;
    const int q   = blockIdx.x >> 3;          // 0..55
    const int h   = xcd * 28 + (q >> 1);      // 0..223, owned by consumer XCD
    const int ch  = q & 1;
    __shared__ u16 tile[64][228];             // row stride 456B -> b64-aligned
#pragma unroll
    for (int i = 0; i < 14; ++i) {            // 64 c-rows * 56 float4 = 3584 units
      int idx = i * 256 + t;
      int c   = idx / 56;
      int wq  = idx % 56;
      float4 v = *(const float4*)(&x[(size_t)(ch * 64 + c) * (HH * WW) + h * WW + wq * 4]);
      uint2 p;
      p.x = (u32)f2bf(v.x) | ((u32)f2bf(v.y) << 16);
      p.y = (u32)f2bf(v.z) | ((u32)f2bf(v.w) << 16);
      *(uint2*)(&tile[c][wq * 4]) = p;
    }
    __syncthreads();
#pragma unroll
    for (int i = 0; i < 7; ++i) {             // 224 w * 8 blocks = 1792
      int idx  = i * 256 + t;
      int ww   = idx >> 3;
      int jcp  = idx & 7;
      int jsrc = jcp ^ (ww & 7);
      uint4 v;
      v.x = (u32)tile[jsrc * 8 + 0][ww] | ((u32)tile[jsrc * 8 + 1][ww] << 16);
      v.y = (u32)tile[jsrc * 8 + 2][ww] | ((u32)tile[jsrc * 8 + 3][ww] << 16);
      v.z = (u32)tile[jsrc * 8 + 4][ww] | ((u32)tile[jsrc * 8 + 5][ww] << 16);
      v.w = (u32)tile[jsrc * 8 + 6][ww] | ((u32)tile[jsrc * 8 + 7][ww] << 16);
      *(uint4*)(&xp[(size_t)ch * PLANE + (size_t)(h * WW + ww) * 64 + jcp * 8]) = v;
    }
  } else {
    int u    = (blockIdx.x - 448) * 256 + t;  // 0..36863 (16B blocks of wp)
    int jcp  = u & 7;
    int mr   = (u >> 3) & 127;
    int rest = u >> 10;                       // ((mt*3+kh)*2+ch)*3+kw
    int kw   = rest % 3;
    int q    = rest / 3;
    int ch   = q & 1;
    int r    = q >> 1;
    int kh   = r % 3;
    int mt   = r / 3;
    int oc   = mt * 128 + mr;
    int cb   = ch * 64 + (jcp ^ (mr & 7)) * 8;
    u16 o[8];
#pragma unroll
    for (int e = 0; e < 8; ++e)
      o[e] = f2bf(w[((size_t)(oc * CIN + cb + e) * 3 + kh) * 3 + kw]);
    uint4 v;
    v.x = (u32)o[0] | ((u32)o[1] << 16);
    v.y = (u32)o[2] | ((u32)o[3] << 16);
    v.z = (u32)o[4] | ((u32)o[5] << 16);
    v.w = (u32)o[6] | ((u32)o[7] << 16);
    *(uint4*)(&wp[(size_t)u * 8]) = v;
  }
}

// ---------------- async global->LDS, 16B per lane ----------------
__device__ __forceinline__ void lds_dma16(const u16* g, u16* l) {
  __builtin_amdgcn_global_load_lds(
      reinterpret_cast<__attribute__((address_space(1))) u32*>(
          reinterpret_cast<uintptr_t>(g)),
      reinterpret_cast<__attribute__((address_space(3))) u32*>(
          reinterpret_cast<uintptr_t>(l)),
      16, 0, 0);
}

// ---------------- main: full-row implicit-GEMM conv ----------------
// grid 448, 1D; xcd = bx&7 owns a 28-row band (both mt halves). Block tile
// M=128 x N=224 (full row). B double-buffered in LDS: DMA for round s+1 is
// issued after round s's barrier and after the first A-frag loads (vmcnt is
// in-order, so A-waits don't wait on the DMA); by the next barrier the DMA
// has had the whole compute phase to land -> drain is free. Epilogue uses
// non-temporal stores: kills the ~50MB output RFO fetch AND the L2 pollution
// that was evicting the banded xp between staging rounds.
__global__ __launch_bounds__(256, 2) void conv_mfma(const u16* __restrict__ wp,
                                                    const u16* __restrict__ xp,
                                                    float* __restrict__ out) {
  __shared__ u16 ldsB[2][226 * 64];  // rows 224..225 stale (feed masked cols only)

  const int tid  = threadIdx.x;
  const int lane = tid & 63;
  const int wave = tid >> 6;
  const int quad = lane >> 4;
  const int lr   = lane & 15;
  const int wm   = wave >> 1;      // wave m-tile 0/1
  const int wn   = wave & 1;       // wave n-tile 0/1

  const int bx  = blockIdx.x;
  const int xcd = bx & 7;
  const int mt  = (bx >> 3) & 1;
  const int oh  = xcd * 28 + (bx >> 4);   // 0..223
  if (oh >= HO) return;                   // 4 idle blocks (uniform exit)

  f32x4 acc[4][7];
#pragma unroll
  for (int i = 0; i < 4; ++i)
#pragma unroll
    for (int j = 0; j < 7; ++j) acc[i][j] = {0.f, 0.f, 0.f, 0.f};

  int swA[2];
#pragma unroll
  for (int ks = 0; ks < 2; ++ks)
    swA[ks] = ((ks * 4 + quad) ^ (lr & 7)) << 3;

  // prologue: stage round 0
  {
    const u16* g0 = xp + (size_t)oh * (WW * 64);   // ch=0, kh=0
#pragma unroll
    for (int uu = 0; uu < 7; ++uu) {
      const int unit = wave * 7 + uu;
      lds_dma16(g0 + unit * 512 + lane * 8, &ldsB[0][unit * 512]);
    }
  }

  for (int s = 0; s < 6; ++s) {
    const int ch = s & 1;
    const int kh = s >> 1;
    const u16* Ab = wp + (size_t)((mt * 3 + kh) * 2 + ch) * 24576 + wm * 4096 + lr * 64;
    const u16* Bbuf = ldsB[s & 1];

    __syncthreads();               // drains DMA(s) (free: issued a full round ago)

    // A-frags for kw=0 FIRST (before next DMA issue -> their vmcnt wait
    // does not include the DMA)
    bf16x8 afp[2][4];
#pragma unroll
    for (int ks = 0; ks < 2; ++ks)
#pragma unroll
      for (int i = 0; i < 4; ++i)
        afp[ks][i] = *reinterpret_cast<const bf16x8*>(Ab + i * 1024 + swA[ks]);

    if (s < 5) {                   // issue DMA for round s+1 into the other buffer
      const int ch2 = (s + 1) & 1;
      const int kh2 = (s + 1) >> 1;
      const u16* g = xp + (size_t)ch2 * PLANE + (size_t)(oh + kh2) * (WW * 64);
      u16* dst = ldsB[(s + 1) & 1];
#pragma unroll
      for (int uu = 0; uu < 7; ++uu) {
        const int unit = wave * 7 + uu;
        lds_dma16(g + unit * 512 + lane * 8, &dst[unit * 512]);
      }
    }

#pragma unroll
    for (int kw = 0; kw < 3; ++kw) {
      const int bq  = (wn * 112 + lr + kw) * 64;     // j=0 row offset in B buffer
      const int sw7 = (lr + kw) & 7;

      bf16x8 afn[2][4];
      if (kw < 2) {                // prefetch next kw's A-frags (covered by MFMA)
#pragma unroll
        for (int ks = 0; ks < 2; ++ks)
#pragma unroll
          for (int i = 0; i < 4; ++i)
            afn[ks][i] = *reinterpret_cast<const bf16x8*>(Ab + (kw + 1) * 8192 + i * 1024 + swA[ks]);
      }

#pragma unroll
      for (int ks = 0; ks < 2; ++ks) {
        const int swB = ((ks * 4 + quad) ^ sw7) << 3;
        bf16x8 bg[7];
#pragma unroll
        for (int j = 0; j < 7; ++j)
          bg[j] = *reinterpret_cast<const bf16x8*>(&Bbuf[bq + j * 1024 + swB]);
#pragma unroll
        for (int i = 0; i < 4; ++i)
#pragma unroll
          for (int j = 0; j < 7; ++j)
            acc[i][j] = __builtin_amdgcn_mfma_f32_16x16x32_bf16(afp[ks][i], bg[j], acc[i][j], 0, 0, 0);
      }

      if (kw < 2) {
#pragma unroll
        for (int ks = 0; ks < 2; ++ks)
#pragma unroll
          for (int i = 0; i < 4; ++i)
            afp[ks][i] = afn[ks][i];
      }
    }
  }

  // epilogue: C/D map col=lane&15, row=quad*4+reg (m89/m91); mask cols 222/223.
  // Non-temporal: no RFO, no L2 pollution.
  const int mb = mt * 128 + wm * 64;
#pragma unroll
  for (int i = 0; i < 4; ++i) {
#pragma unroll
    for (int j = 0; j < 7; ++j) {
      const int col = wn * 112 + j * 16 + lr;
      if (col < WO) {
        float* op = out + (size_t)(mb + i * 16 + quad * 4) * (HO * WO) +
                    (size_t)oh * WO + col;
#pragma unroll
        for (int r = 0; r < 4; ++r)
          __builtin_nontemporal_store(acc[i][j][r], op + (size_t)r * (HO * WO));
      }
    }
  }
}

// ---------------- fallback (ws too small): naive fp32 direct conv ----------------
__global__ void conv_naive(const float* __restrict__ x, const float* __restrict__ w,
                           float* __restrict__ out) {
  int idx = blockIdx.x * 256 + threadIdx.x;
  if (idx >= COUT * HO * WO) return;
  int ow  = idx % WO;
  int tmp = idx / WO;
  int oh  = tmp % HO;
  int oc  = tmp / HO;
  float s = 0.f;
  for (int c = 0; c < CIN; ++c)
    for (int kh = 0; kh < 3; ++kh) {
      const float* xr = &x[(size_t)(c * HH + oh + kh) * WW + ow];
      const float* wr = &w[((size_t)(oc * CIN + c) * 3 + kh) * 3];
      s += xr[0] * wr[0] + xr[1] * wr[1] + xr[2] * wr[2];
    }
  out[idx] = s;
}

extern "C" void kernel_launch(void* const* d_in, const int* in_sizes, int n_in,
                              void* d_out, int out_size, void* d_ws, size_t ws_size,
                              hipStream_t stream) {
  const float* x    = (const float*)d_in[0];
  const float* kern = (const float*)d_in[1];
  float* out        = (float*)d_out;

  const size_t WP_BYTES = (size_t)36864 * 16;        // 589,824
  const size_t XP_BYTES = (size_t)2 * PLANE * 2;     // 12,845,056

  if (ws_size >= WP_BYTES + XP_BYTES) {
    u16* wp = (u16*)d_ws;
    u16* xp = (u16*)((char*)d_ws + WP_BYTES);
    hipLaunchKernelGGL(prep, dim3(592), dim3(256), 0, stream, x, kern, xp, wp);
    hipLaunchKernelGGL(conv_mfma, dim3(448), dim3(256), 0, stream, wp, xp, out);
  } else {
    int total = COUT * HO * WO;
    hipLaunchKernelGGL(conv_naive, dim3((total + 255) / 256), dim3(256), 0, stream,
                       x, kern, out);
  }
}

// Round 5
// 120.732 us; speedup vs baseline: 1.0889x; 1.0889x over previous
//
#include <hip/hip_runtime.h>

#define CIN   128
#define HH    224
#define WW    224
#define COUT  256
#define HO    222
#define WO    222

typedef unsigned short u16;
typedef unsigned int   u32;
typedef __bf16  bf16x8 __attribute__((ext_vector_type(8)));
typedef float   f32x4  __attribute__((ext_vector_type(4)));

__device__ __forceinline__ u16 f2bf(float f) {
  union { float f; u32 u; } v; v.f = f;
  u32 u = v.u;
  return (u16)((u + 0x7FFFu + ((u >> 16) & 1u)) >> 16);  // RNE
}

// ---------------- merged pre-pass ----------------
// blocks 0..223: pack x -> xp [h(224)][w(224)][jc'(16)][e(8)] bf16 (full K=128
//   per pixel, contiguous 256B). Physical block jc' holds source c-block
//   jc' ^ (w&15) (bank/granule swizzle). XCD-aligned with the consumer:
//   conv band k (=bx&7 under round-robin dispatch) reads rows k*28..k*28+29,
//   so row h is packed on XCD h/28 -> lands dirty in the consumer's L2.
// blocks 224..367: pack w -> wp [mt(2)][kh(3)][ch(2)][kw(3)][mr(128)][jc'(8)][e(8)],
//   block jc' holds c-block jc'^(mr&7).
__global__ void prep(const float* __restrict__ x, const float* __restrict__ w,
                     u16* __restrict__ xp, u16* __restrict__ wp) {
  const int t = threadIdx.x;
  if (blockIdx.x < 224) {
    const int xcd = blockIdx.x & 7;
    const int h   = xcd * 28 + (blockIdx.x >> 3);   // owned by consumer XCD
    __shared__ u16 tile[128][228];                  // row stride 456B, b64-aligned
#pragma unroll
    for (int i = 0; i < 28; ++i) {                  // 128 c-rows * 56 float4
      int idx = i * 256 + t;
      int c   = idx / 56;
      int wq  = idx % 56;
      float4 v = *(const float4*)(&x[(size_t)c * (HH * WW) + h * WW + wq * 4]);
      uint2 p;
      p.x = (u32)f2bf(v.x) | ((u32)f2bf(v.y) << 16);
      p.y = (u32)f2bf(v.z) | ((u32)f2bf(v.w) << 16);
      *(uint2*)(&tile[c][wq * 4]) = p;
    }
    __syncthreads();
#pragma unroll
    for (int i = 0; i < 14; ++i) {                  // 224 w * 16 blocks = 3584
      int idx  = i * 256 + t;
      int ww   = idx >> 4;
      int jcp  = idx & 15;
      int jsrc = jcp ^ (ww & 15);
      uint4 v;
      v.x = (u32)tile[jsrc * 8 + 0][ww] | ((u32)tile[jsrc * 8 + 1][ww] << 16);
      v.y = (u32)tile[jsrc * 8 + 2][ww] | ((u32)tile[jsrc * 8 + 3][ww] << 16);
      v.z = (u32)tile[jsrc * 8 + 4][ww] | ((u32)tile[jsrc * 8 + 5][ww] << 16);
      v.w = (u32)tile[jsrc * 8 + 6][ww] | ((u32)tile[jsrc * 8 + 7][ww] << 16);
      *(uint4*)(&xp[((size_t)h * WW + ww) * 128 + jcp * 8]) = v;
    }
  } else {
    int u    = (blockIdx.x - 224) * 256 + t;  // 0..36863 (16B blocks of wp)
    int jcp  = u & 7;
    int mr   = (u >> 3) & 127;
    int rest = u >> 10;                       // ((mt*3+kh)*2+ch)*3+kw
    int kw   = rest % 3;
    int q    = rest / 3;
    int ch   = q & 1;
    int r    = q >> 1;
    int kh   = r % 3;
    int mt   = r / 3;
    int oc   = mt * 128 + mr;
    int cb   = ch * 64 + (jcp ^ (mr & 7)) * 8;
    u16 o[8];
#pragma unroll
    for (int e = 0; e < 8; ++e)
      o[e] = f2bf(w[((size_t)(oc * CIN + cb + e) * 3 + kh) * 3 + kw]);
    uint4 v;
    v.x = (u32)o[0] | ((u32)o[1] << 16);
    v.y = (u32)o[2] | ((u32)o[3] << 16);
    v.z = (u32)o[4] | ((u32)o[5] << 16);
    v.w = (u32)o[6] | ((u32)o[7] << 16);
    *(uint4*)(&wp[(size_t)u * 8]) = v;
  }
}

// ---------------- async global->LDS, 16B per lane ----------------
__device__ __forceinline__ void lds_dma16(const u16* g, u16* l) {
  __builtin_amdgcn_global_load_lds(
      reinterpret_cast<__attribute__((address_space(1))) u32*>(
          reinterpret_cast<uintptr_t>(g)),
      reinterpret_cast<__attribute__((address_space(3))) u32*>(
          reinterpret_cast<uintptr_t>(l)),
      16, 0, 0);
}

// ---------------- main: full-row implicit-GEMM conv ----------------
// grid 448, 1D; xcd = bx&7 owns a 28-row band (both mt halves) -> staging DMAs
// hit the L2 lines prep left dirty. Block tile M=128 x N=224 (full row), full
// K=128 staged per round: 3 rounds (kh), 6 barriers total. All 3 kw reuse the
// staged row (reads shift 256B/pixel). A-frags load global->VGPR from
// L2-resident packed weights. Wave tile 64x112 = 4x7 frags of 16x16x32.
// Normal (cached) epilogue stores: partial-sector writes merge in L2
// (NT stores measured +35% WRITE_SIZE and +10us — R4).
__global__ __launch_bounds__(256, 2) void conv_mfma(const u16* __restrict__ wp,
                                                    const u16* __restrict__ xp,
                                                    float* __restrict__ out) {
  __shared__ u16 ldsB[226 * 128];  // 57856B; pixels 224..225 stale (masked cols only)

  const int tid  = threadIdx.x;
  const int lane = tid & 63;
  const int wave = tid >> 6;
  const int quad = lane >> 4;
  const int lr   = lane & 15;
  const int wm   = wave >> 1;      // wave m-tile 0/1
  const int wn   = wave & 1;       // wave n-tile 0/1

  const int bx  = blockIdx.x;
  const int xcd = bx & 7;
  const int mt  = (bx >> 3) & 1;
  const int oh  = xcd * 28 + (bx >> 4);   // 0..223
  if (oh >= HO) return;                   // 4 idle blocks (uniform exit)

  f32x4 acc[4][7];
#pragma unroll
  for (int i = 0; i < 4; ++i)
#pragma unroll
    for (int j = 0; j < 7; ++j) acc[i][j] = {0.f, 0.f, 0.f, 0.f};

  int swA[2];
#pragma unroll
  for (int k2 = 0; k2 < 2; ++k2)
    swA[k2] = ((k2 * 4 + quad) ^ (lr & 7)) << 3;

  for (int kh = 0; kh < 3; ++kh) {
    const u16* g = xp + (size_t)(oh + kh) * (WW * 128);

    __syncthreads();               // WAR: prev round's B reads done before overwrite
#pragma unroll
    for (int uu = 0; uu < 14; ++uu) {
      const int unit = wave * 14 + uu;          // 56 x 1KB units = full row, K=128
      lds_dma16(g + unit * 512 + lane * 8, &ldsB[unit * 512]);
    }
    __syncthreads();               // drain -> LDS valid

    const u16* Ab = wp + (size_t)(mt * 3 + kh) * 2 * 24576 + wm * 4096 + lr * 64;

#pragma unroll
    for (int kw = 0; kw < 3; ++kw) {
      const int bq   = (wn * 112 + lr + kw) * 128;   // j=0 pixel offset in ldsB
      const int sw15 = (lr + kw) & 15;
#pragma unroll
      for (int ks = 0; ks < 4; ++ks) {               // k-chunk: ch = ks>>1
        const int swB = ((ks * 4 + quad) ^ sw15) << 3;
        const u16* Ak = Ab + (ks >> 1) * 24576 + kw * 8192;
        bf16x8 af[4], bg[7];
#pragma unroll
        for (int i = 0; i < 4; ++i)
          af[i] = *reinterpret_cast<const bf16x8*>(Ak + i * 1024 + swA[ks & 1]);
#pragma unroll
        for (int j = 0; j < 7; ++j)
          bg[j] = *reinterpret_cast<const bf16x8*>(&ldsB[bq + j * 2048 + swB]);
#pragma unroll
        for (int i = 0; i < 4; ++i)
#pragma unroll
          for (int j = 0; j < 7; ++j)
            acc[i][j] = __builtin_amdgcn_mfma_f32_16x16x32_bf16(af[i], bg[j], acc[i][j], 0, 0, 0);
      }
    }
  }

  // epilogue: C/D map col=lane&15, row=quad*4+reg (m89/m91); mask cols 222/223
  const int mb = mt * 128 + wm * 64;
#pragma unroll
  for (int i = 0; i < 4; ++i) {
#pragma unroll
    for (int j = 0; j < 7; ++j) {
      const int col = wn * 112 + j * 16 + lr;
      if (col < WO) {
        float* op = out + (size_t)(mb + i * 16 + quad * 4) * (HO * WO) +
                    (size_t)oh * WO + col;
#pragma unroll
        for (int r = 0; r < 4; ++r)
          op[(size_t)r * (HO * WO)] = acc[i][j][r];
      }
    }
  }
}

// ---------------- fallback (ws too small): naive fp32 direct conv ----------------
__global__ void conv_naive(const float* __restrict__ x, const float* __restrict__ w,
                           float* __restrict__ out) {
  int idx = blockIdx.x * 256 + threadIdx.x;
  if (idx >= COUT * HO * WO) return;
  int ow  = idx % WO;
  int tmp = idx / WO;
  int oh  = tmp % HO;
  int oc  = tmp / HO;
  float s = 0.f;
  for (int c = 0; c < CIN; ++c)
    for (int kh = 0; kh < 3; ++kh) {
      const float* xr = &x[(size_t)(c * HH + oh + kh) * WW + ow];
      const float* wr = &w[((size_t)(oc * CIN + c) * 3 + kh) * 3];
      s += xr[0] * wr[0] + xr[1] * wr[1] + xr[2] * wr[2];
    }
  out[idx] = s;
}

extern "C" void kernel_launch(void* const* d_in, const int* in_sizes, int n_in,
                              void* d_out, int out_size, void* d_ws, size_t ws_size,
                              hipStream_t stream) {
  const float* x    = (const float*)d_in[0];
  const float* kern = (const float*)d_in[1];
  float* out        = (float*)d_out;

  const size_t WP_BYTES = (size_t)36864 * 16;            // 589,824
  const size_t XP_BYTES = (size_t)HH * WW * 128 * 2;     // 12,845,056

  if (ws_size >= WP_BYTES + XP_BYTES) {
    u16* wp = (u16*)d_ws;
    u16* xp = (u16*)((char*)d_ws + WP_BYTES);
    hipLaunchKernelGGL(prep, dim3(368), dim3(256), 0, stream, x, kern, xp, wp);
    hipLaunchKernelGGL(conv_mfma, dim3(448), dim3(256), 0, stream, wp, xp, out);
  } else {
    int total = COUT * HO * WO;
    hipLaunchKernelGGL(conv_naive, dim3((total + 255) / 256), dim3(256), 0, stream,
                       x, kern, out);
  }
}

// Round 6
// 118.978 us; speedup vs baseline: 1.1050x; 1.0147x over previous
//
#include <hip/hip_runtime.h>

#define CIN   128
#define HH    224
#define WW    224
#define COUT  256
#define HO    222
#define WO    222

typedef unsigned short u16;
typedef unsigned int   u32;
typedef __bf16  bf16x8 __attribute__((ext_vector_type(8)));
typedef float   f32x4  __attribute__((ext_vector_type(4)));

__device__ __forceinline__ u16 f2bf(float f) {
  union { float f; u32 u; } v; v.f = f;
  u32 u = v.u;
  return (u16)((u + 0x7FFFu + ((u >> 16) & 1u)) >> 16);  // RNE
}

// ---------------- merged pre-pass (load-balanced: 448 x-blocks + 144 w-blocks) ----------------
// x-pack: block handles one (h, w-half); XCD-aligned with consumer band (row h
//   packed on XCD h/28, the L2 that conv's DMA will read). xp layout:
//   [h(224)][w(224)][jc'(16)][e(8)] bf16; physical block jc' holds source
//   c-block jc' ^ (w&15)  (bank/granule swizzle).
// w-pack: wp [mt(2)][kh(3)][ch(2)][kw(3)][mr(128)][jc'(8)][e(8)], jc' holds jc'^(mr&7).
__global__ void prep(const float* __restrict__ x, const float* __restrict__ w,
                     u16* __restrict__ xp, u16* __restrict__ wp) {
  const int t = threadIdx.x;
  if (blockIdx.x < 448) {
    const int xcd = blockIdx.x & 7;
    const int q   = blockIdx.x >> 3;          // 0..55
    const int h   = xcd * 28 + (q >> 1);      // 0..223, owned by consumer XCD
    const int wb  = q & 1;                    // w-half
    __shared__ u16 tile[128][116];            // 29.7 KB; row 232B
#pragma unroll
    for (int i = 0; i < 14; ++i) {            // 128 c-rows * 28 float4 = 3584 units
      int idx = i * 256 + t;
      int c   = idx / 28;
      int wq  = idx % 28;
      float4 v = *(const float4*)(&x[(size_t)c * (HH * WW) + h * WW + wb * 112 + wq * 4]);
      uint2 p;
      p.x = (u32)f2bf(v.x) | ((u32)f2bf(v.y) << 16);
      p.y = (u32)f2bf(v.z) | ((u32)f2bf(v.w) << 16);
      *(uint2*)(&tile[c][wq * 4]) = p;
    }
    __syncthreads();
#pragma unroll
    for (int i = 0; i < 7; ++i) {             // 112 w * 16 blocks = 1792
      int idx  = i * 256 + t;
      int wl   = idx >> 4;                    // 0..111
      int jcp  = idx & 15;
      int ww   = wb * 112 + wl;
      int jsrc = jcp ^ (ww & 15);
      uint4 v;
      v.x = (u32)tile[jsrc * 8 + 0][wl] | ((u32)tile[jsrc * 8 + 1][wl] << 16);
      v.y = (u32)tile[jsrc * 8 + 2][wl] | ((u32)tile[jsrc * 8 + 3][wl] << 16);
      v.z = (u32)tile[jsrc * 8 + 4][wl] | ((u32)tile[jsrc * 8 + 5][wl] << 16);
      v.w = (u32)tile[jsrc * 8 + 6][wl] | ((u32)tile[jsrc * 8 + 7][wl] << 16);
      *(uint4*)(&xp[((size_t)h * WW + ww) * 128 + jcp * 8]) = v;
    }
  } else {
    int u    = (blockIdx.x - 448) * 256 + t;  // 0..36863 (16B blocks of wp)
    int jcp  = u & 7;
    int mr   = (u >> 3) & 127;
    int rest = u >> 10;                       // ((mt*3+kh)*2+ch)*3+kw
    int kw   = rest % 3;
    int q    = rest / 3;
    int ch   = q & 1;
    int r    = q >> 1;
    int kh   = r % 3;
    int mt   = r / 3;
    int oc   = mt * 128 + mr;
    int cb   = ch * 64 + (jcp ^ (mr & 7)) * 8;
    u16 o[8];
#pragma unroll
    for (int e = 0; e < 8; ++e)
      o[e] = f2bf(w[((size_t)(oc * CIN + cb + e) * 3 + kh) * 3 + kw]);
    uint4 v;
    v.x = (u32)o[0] | ((u32)o[1] << 16);
    v.y = (u32)o[2] | ((u32)o[3] << 16);
    v.z = (u32)o[4] | ((u32)o[5] << 16);
    v.w = (u32)o[6] | ((u32)o[7] << 16);
    *(uint4*)(&wp[(size_t)u * 8]) = v;
  }
}

// ---------------- async global->LDS, 16B per lane ----------------
__device__ __forceinline__ void lds_dma16(const u16* g, u16* l) {
  __builtin_amdgcn_global_load_lds(
      reinterpret_cast<__attribute__((address_space(1))) u32*>(
          reinterpret_cast<uintptr_t>(g)),
      reinterpret_cast<__attribute__((address_space(3))) u32*>(
          reinterpret_cast<uintptr_t>(l)),
      16, 0, 0);
}

// ---------------- main: full-row implicit-GEMM conv ----------------
// grid 448, 1D; xcd = bx&7 owns a 28-row band. Block tile M=128 x N=224 (full
// row), full K=128 staged per round: 3 rounds (kh). A-frags: ALL 16 dwordx4
// for a kw loaded in ONE batch (one vmcnt window) before the ks-loop — drops
// exposed A-latencies per wave from 36 to 9 (VGPR 56 -> ~200; we are
// grid-limited at 2 blocks/CU so the register headroom is free).
__global__ __launch_bounds__(256, 2) void conv_mfma(const u16* __restrict__ wp,
                                                    const u16* __restrict__ xp,
                                                    float* __restrict__ out) {
  __shared__ u16 ldsB[226 * 128];  // 57856B; pixels 224..225 stale (masked cols only)

  const int tid  = threadIdx.x;
  const int lane = tid & 63;
  const int wave = tid >> 6;
  const int quad = lane >> 4;
  const int lr   = lane & 15;
  const int wm   = wave >> 1;      // wave m-tile 0/1
  const int wn   = wave & 1;       // wave n-tile 0/1

  const int bx  = blockIdx.x;
  const int xcd = bx & 7;
  const int mt  = (bx >> 3) & 1;
  const int oh  = xcd * 28 + (bx >> 4);   // 0..223
  if (oh >= HO) return;                   // 4 idle blocks (uniform exit)

  f32x4 acc[4][7];
#pragma unroll
  for (int i = 0; i < 4; ++i)
#pragma unroll
    for (int j = 0; j < 7; ++j) acc[i][j] = {0.f, 0.f, 0.f, 0.f};

  int swA[2];
#pragma unroll
  for (int k2 = 0; k2 < 2; ++k2)
    swA[k2] = ((k2 * 4 + quad) ^ (lr & 7)) << 3;

  for (int kh = 0; kh < 3; ++kh) {
    const u16* g = xp + (size_t)(oh + kh) * (WW * 128);

    __syncthreads();               // WAR: prev round's B reads done before overwrite
#pragma unroll
    for (int uu = 0; uu < 14; ++uu) {
      const int unit = wave * 14 + uu;          // 56 x 1KB units = full row, K=128
      lds_dma16(g + unit * 512 + lane * 8, &ldsB[unit * 512]);
    }
    __syncthreads();               // drain -> LDS valid

    const u16* Ab = wp + (size_t)(mt * 3 + kh) * 2 * 24576 + wm * 4096 + lr * 64;

#pragma unroll
    for (int kw = 0; kw < 3; ++kw) {
      // ---- batched A: 16 loads, one vmcnt window ----
      bf16x8 af[4][4];             // [ks][i]
#pragma unroll
      for (int ks = 0; ks < 4; ++ks) {
        const u16* Ak = Ab + (ks >> 1) * 24576 + kw * 8192;
#pragma unroll
        for (int i = 0; i < 4; ++i)
          af[ks][i] = *reinterpret_cast<const bf16x8*>(Ak + i * 1024 + swA[ks & 1]);
      }

      const int bq   = (wn * 112 + lr + kw) * 128;   // j=0 pixel offset in ldsB
      const int sw15 = (lr + kw) & 15;
#pragma unroll
      for (int ks = 0; ks < 4; ++ks) {               // k-chunk: ch = ks>>1
        const int swB = ((ks * 4 + quad) ^ sw15) << 3;
        bf16x8 bg[7];
#pragma unroll
        for (int j = 0; j < 7; ++j)
          bg[j] = *reinterpret_cast<const bf16x8*>(&ldsB[bq + j * 2048 + swB]);
#pragma unroll
        for (int i = 0; i < 4; ++i)
#pragma unroll
          for (int j = 0; j < 7; ++j)
            acc[i][j] = __builtin_amdgcn_mfma_f32_16x16x32_bf16(af[ks][i], bg[j], acc[i][j], 0, 0, 0);
      }
    }
  }

  // epilogue: C/D map col=lane&15, row=quad*4+reg (m89/m91); mask cols 222/223
  const int mb = mt * 128 + wm * 64;
#pragma unroll
  for (int i = 0; i < 4; ++i) {
#pragma unroll
    for (int j = 0; j < 7; ++j) {
      const int col = wn * 112 + j * 16 + lr;
      if (col < WO) {
        float* op = out + (size_t)(mb + i * 16 + quad * 4) * (HO * WO) +
                    (size_t)oh * WO + col;
#pragma unroll
        for (int r = 0; r < 4; ++r)
          op[(size_t)r * (HO * WO)] = acc[i][j][r];
      }
    }
  }
}

// ---------------- fallback (ws too small): naive fp32 direct conv ----------------
__global__ void conv_naive(const float* __restrict__ x, const float* __restrict__ w,
                           float* __restrict__ out) {
  int idx = blockIdx.x * 256 + threadIdx.x;
  if (idx >= COUT * HO * WO) return;
  int ow  = idx % WO;
  int tmp = idx / WO;
  int oh  = tmp % HO;
  int oc  = tmp / HO;
  float s = 0.f;
  for (int c = 0; c < CIN; ++c)
    for (int kh = 0; kh < 3; ++kh) {
      const float* xr = &x[(size_t)(c * HH + oh + kh) * WW + ow];
      const float* wr = &w[((size_t)(oc * CIN + c) * 3 + kh) * 3];
      s += xr[0] * wr[0] + xr[1] * wr[1] + xr[2] * wr[2];
    }
  out[idx] = s;
}

extern "C" void kernel_launch(void* const* d_in, const int* in_sizes, int n_in,
                              void* d_out, int out_size, void* d_ws, size_t ws_size,
                              hipStream_t stream) {
  const float* x    = (const float*)d_in[0];
  const float* kern = (const float*)d_in[1];
  float* out        = (float*)d_out;

  const size_t WP_BYTES = (size_t)36864 * 16;            // 589,824
  const size_t XP_BYTES = (size_t)HH * WW * 128 * 2;     // 12,845,056

  if (ws_size >= WP_BYTES + XP_BYTES) {
    u16* wp = (u16*)d_ws;
    u16* xp = (u16*)((char*)d_ws + WP_BYTES);
    hipLaunchKernelGGL(prep, dim3(592), dim3(256), 0, stream, x, kern, xp, wp);
    hipLaunchKernelGGL(conv_mfma, dim3(448), dim3(256), 0, stream, wp, xp, out);
  } else {
    int total = COUT * HO * WO;
    hipLaunchKernelGGL(conv_naive, dim3((total + 255) / 256), dim3(256), 0, stream,
                       x, kern, out);
  }
}